// Round 1
// baseline (2812.372 us; speedup 1.0000x reference)
//
#include <hip/hip_runtime.h>

#define BATCH   8192
#define DIMN    64
#define HIDN    128
#define N_STEPS 100
#define RT      32          // rows per block
#define XS      68          // x tile stride (floats), 16B-aligned rows, +4-bank skew
#define HS      132         // h tile stride (floats), 16B-aligned rows, +4-bank skew
#define DT      0.01f
#define SQDT    0.1f

__device__ __forceinline__ float fast_tanh(float a) {
    // tanh(a) = 1 - 2/(exp(2a)+1); exact at +-inf saturation
    float e = __expf(2.0f * a);
    return 1.0f - 2.0f * __builtin_amdgcn_rcpf(e + 1.0f);
}

__global__ __launch_bounds__(256, 1)
void sde_kernel(const float* __restrict__ x0,
                const float* __restrict__ noise,
                const float* __restrict__ Wd1, const float* __restrict__ bd1,
                const float* __restrict__ Wd2, const float* __restrict__ bd2,
                const float* __restrict__ Wg1, const float* __restrict__ bg1,
                const float* __restrict__ Wg2, const float* __restrict__ bg2,
                float* __restrict__ out)
{
    // 131072 + 1536 + 8704 + 16896 = 158208 B  (< 160 KiB/CU)
    __shared__ float sW1d[DIMN * HIDN];   // [64][128] row-major
    __shared__ float sW2d[HIDN * DIMN];   // [128][64] row-major
    __shared__ float sW1g[DIMN * HIDN];
    __shared__ float sW2g[HIDN * DIMN];
    __shared__ float sbias[2 * (HIDN + DIMN)];
    __shared__ float sx[RT * XS];
    __shared__ float sh[RT * HS];

    const int t = threadIdx.x;

    // ---- stage weights into LDS (once per block) ----
    for (int i = t; i < DIMN * HIDN / 4; i += 256) {
        ((float4*)sW1d)[i] = ((const float4*)Wd1)[i];
        ((float4*)sW2d)[i] = ((const float4*)Wd2)[i];
        ((float4*)sW1g)[i] = ((const float4*)Wg1)[i];
        ((float4*)sW2g)[i] = ((const float4*)Wg2)[i];
    }
    if (t < HIDN) sbias[t] = bd1[t];
    if (t < DIMN) sbias[HIDN + t] = bd2[t];
    if (t < HIDN) sbias[HIDN + DIMN + t] = bg1[t];
    if (t < DIMN) sbias[2 * HIDN + DIMN + t] = bg2[t];

    const long row0 = (long)blockIdx.x * RT;

    // ---- x0 -> sx tile, and out[0] = x0 ----
    for (int i = t; i < RT * DIMN / 4; i += 256) {
        int r = i >> 4, c4 = i & 15;
        float4 v = ((const float4*)(x0 + row0 * DIMN))[i];
        *(float4*)(sx + r * XS + 4 * c4) = v;
        ((float4*)(out + row0 * DIMN))[i] = v;
    }
    __syncthreads();

    // layer-1 mapping: col c1 in [0,128), 16 rows starting at r1
    const int c1 = t & 127;
    const int r1 = (t >> 7) * 16;
    // layer-2 / update mapping: col c2 in [0,64), 8 rows starting at r2
    const int c2 = t & 63;
    const int r2 = (t >> 6) * 8;

    const float b1d = sbias[c1];
    const float b2d = sbias[HIDN + c2];
    const float b1g = sbias[HIDN + DIMN + c1];
    const float b2g = sbias[2 * HIDN + DIMN + c2];

    float fv[8], gv[8];

    for (int s = 0; s < N_STEPS; ++s) {
        // ---------- hd = tanh(x @ Wd1 + bd1) ----------
        {
            float acc[16];
            #pragma unroll
            for (int i = 0; i < 16; ++i) acc[i] = b1d;
            #pragma unroll 4
            for (int k = 0; k < DIMN; k += 4) {
                float w0 = sW1d[(k + 0) * HIDN + c1];
                float w1 = sW1d[(k + 1) * HIDN + c1];
                float w2 = sW1d[(k + 2) * HIDN + c1];
                float w3 = sW1d[(k + 3) * HIDN + c1];
                #pragma unroll
                for (int i = 0; i < 16; ++i) {
                    float4 xv = *(const float4*)(sx + (r1 + i) * XS + k);
                    acc[i] = fmaf(xv.x, w0, acc[i]);
                    acc[i] = fmaf(xv.y, w1, acc[i]);
                    acc[i] = fmaf(xv.z, w2, acc[i]);
                    acc[i] = fmaf(xv.w, w3, acc[i]);
                }
            }
            #pragma unroll
            for (int i = 0; i < 16; ++i) sh[(r1 + i) * HS + c1] = fast_tanh(acc[i]);
        }
        __syncthreads();

        // ---------- f = hd @ Wd2 + bd2 ----------
        {
            float acc[8];
            #pragma unroll
            for (int i = 0; i < 8; ++i) acc[i] = b2d;
            #pragma unroll 4
            for (int k = 0; k < HIDN; k += 4) {
                float w0 = sW2d[(k + 0) * DIMN + c2];
                float w1 = sW2d[(k + 1) * DIMN + c2];
                float w2 = sW2d[(k + 2) * DIMN + c2];
                float w3 = sW2d[(k + 3) * DIMN + c2];
                #pragma unroll
                for (int i = 0; i < 8; ++i) {
                    float4 hv = *(const float4*)(sh + (r2 + i) * HS + k);
                    acc[i] = fmaf(hv.x, w0, acc[i]);
                    acc[i] = fmaf(hv.y, w1, acc[i]);
                    acc[i] = fmaf(hv.z, w2, acc[i]);
                    acc[i] = fmaf(hv.w, w3, acc[i]);
                }
            }
            #pragma unroll
            for (int i = 0; i < 8; ++i) fv[i] = acc[i];
        }
        __syncthreads();

        // ---------- hg = tanh(x @ Wg1 + bg1) ----------
        {
            float acc[16];
            #pragma unroll
            for (int i = 0; i < 16; ++i) acc[i] = b1g;
            #pragma unroll 4
            for (int k = 0; k < DIMN; k += 4) {
                float w0 = sW1g[(k + 0) * HIDN + c1];
                float w1 = sW1g[(k + 1) * HIDN + c1];
                float w2 = sW1g[(k + 2) * HIDN + c1];
                float w3 = sW1g[(k + 3) * HIDN + c1];
                #pragma unroll
                for (int i = 0; i < 16; ++i) {
                    float4 xv = *(const float4*)(sx + (r1 + i) * XS + k);
                    acc[i] = fmaf(xv.x, w0, acc[i]);
                    acc[i] = fmaf(xv.y, w1, acc[i]);
                    acc[i] = fmaf(xv.z, w2, acc[i]);
                    acc[i] = fmaf(xv.w, w3, acc[i]);
                }
            }
            #pragma unroll
            for (int i = 0; i < 16; ++i) sh[(r1 + i) * HS + c1] = fast_tanh(acc[i]);
        }
        __syncthreads();

        // ---------- g = hg @ Wg2 + bg2 ----------
        {
            float acc[8];
            #pragma unroll
            for (int i = 0; i < 8; ++i) acc[i] = b2g;
            #pragma unroll 4
            for (int k = 0; k < HIDN; k += 4) {
                float w0 = sW2g[(k + 0) * DIMN + c2];
                float w1 = sW2g[(k + 1) * DIMN + c2];
                float w2 = sW2g[(k + 2) * DIMN + c2];
                float w3 = sW2g[(k + 3) * DIMN + c2];
                #pragma unroll
                for (int i = 0; i < 8; ++i) {
                    float4 hv = *(const float4*)(sh + (r2 + i) * HS + k);
                    acc[i] = fmaf(hv.x, w0, acc[i]);
                    acc[i] = fmaf(hv.y, w1, acc[i]);
                    acc[i] = fmaf(hv.z, w2, acc[i]);
                    acc[i] = fmaf(hv.w, w3, acc[i]);
                }
            }
            #pragma unroll
            for (int i = 0; i < 8; ++i) gv[i] = acc[i];
        }

        // ---------- x += f*dt + g*(dw*sqrt_dt); write traj ----------
        {
            const float* nz = noise + (long)s * BATCH * DIMN + (row0 + r2) * DIMN + c2;
            float* op = out + (long)(s + 1) * BATCH * DIMN + (row0 + r2) * DIMN + c2;
            #pragma unroll
            for (int i = 0; i < 8; ++i) {
                float dw = nz[(long)i * DIMN];
                float xv = sx[(r2 + i) * XS + c2];
                float xn = fmaf(fv[i], DT, fmaf(gv[i] * dw, SQDT, xv));
                sx[(r2 + i) * XS + c2] = xn;
                op[(long)i * DIMN] = xn;
            }
        }
        __syncthreads();
    }
}

extern "C" void kernel_launch(void* const* d_in, const int* in_sizes, int n_in,
                              void* d_out, int out_size, void* d_ws, size_t ws_size,
                              hipStream_t stream) {
    const float* x0    = (const float*)d_in[0];
    // d_in[1] = t_span (unused; MLPs ignore t)
    const float* noise = (const float*)d_in[2];
    const float* Wd1   = (const float*)d_in[3];
    const float* bd1   = (const float*)d_in[4];
    const float* Wd2   = (const float*)d_in[5];
    const float* bd2   = (const float*)d_in[6];
    const float* Wg1   = (const float*)d_in[7];
    const float* bg1   = (const float*)d_in[8];
    const float* Wg2   = (const float*)d_in[9];
    const float* bg2   = (const float*)d_in[10];
    float* out = (float*)d_out;

    sde_kernel<<<BATCH / RT, 256, 0, stream>>>(
        x0, noise, Wd1, bd1, Wd2, bd2, Wg1, bg1, Wg2, bg2, out);
}